// Round 9
// baseline (188.385 us; speedup 1.0000x reference)
//
#include <hip/hip_runtime.h>
#include <math.h>

#define NN 131072
#define KK 27
#define FIN 3
#define FOUT 32
#define EPS 1e-5f

typedef _Float16 f16;
typedef __attribute__((ext_vector_type(8))) _Float16 f16x8;
typedef __attribute__((ext_vector_type(4)))  float   f32x4;
typedef __attribute__((ext_vector_type(16))) float   f32x16;

// ---------------------------------------------------------------------------
// Dispatch 0: prep. Blocks < NN/256 build xpad [N] float4 (x,y,z,0) so conv1
// gathers are 1 probe (16B) instead of 3 dword probes. Tail blocks pack w2
// into f16 MFMA B-frags w2p[k][half][lane][j]; B layout for
// v_mfma_f32_32x32x16: col = lane&31, kdim = (lane>>5)*8 + j (proven r1).
// ---------------------------------------------------------------------------
__global__ __launch_bounds__(256) void prep_kernel(
    const float* __restrict__ x, float4* __restrict__ xp,
    const float* __restrict__ w2, f16* __restrict__ w2p)
{
    if (blockIdx.x >= NN / 256) {                    // tail: pack one w2 tap
        const int k = blockIdx.x - NN / 256;
        const int t = threadIdx.x;
#pragma unroll
        for (int r = 0; r < 4; ++r) {
            const int e    = r * 256 + t;
            const int half = e >> 9;
            const int l    = (e >> 3) & 63;
            const int j    = e & 7;
            const int krow = half * 16 + ((l >> 5) << 3) + j;
            const int n    = l & 31;
            w2p[k * 1024 + e] = (f16)w2[k * (FOUT * FOUT) + krow * FOUT + n];
        }
        return;
    }
    const int n = blockIdx.x * 256 + threadIdx.x;
    const float* r = x + (size_t)n * 3;
    xp[n] = make_float4(r[0], r[1], r[2], 0.f);
}

// ---------------------------------------------------------------------------
// Dispatch 1: conv1. h = silu(bn1(einsum(x[nbr], w1))) -> [N,32] f16.
// Gathers are single dwordx4 from xpad (2 MB table -> per-XCD L2 resident,
// 3x fewer probes than 3-dword). 9-slot asm window, counted vmcnt (never 0
// until tail) + sched_barrier(0) -- the r8 pattern that produced conv2's
// first real gain. w1 stays raw f32 input (uniform s_loads).
// ---------------------------------------------------------------------------
__global__ __launch_bounds__(256, 2) void conv1_kernel(
    const float4* __restrict__ xpad,     // [N] padded x
    const int*    __restrict__ nbr_idx,  // [N,27]
    const float*  __restrict__ w1,       // [27,3,32]
    const float* __restrict__ g1,  const float* __restrict__ b1,
    const float* __restrict__ m1,  const float* __restrict__ v1,
    f16* __restrict__ h_out)             // [N,32] f16
{
    const int n = blockIdx.x * 256 + threadIdx.x;

    int idxs[KK];
    const int* nb = nbr_idx + (size_t)n * KK;
#pragma unroll
    for (int k = 0; k < KK; ++k) idxs[k] = nb[k];
#pragma unroll
    for (int k = 0; k < KK; ++k) asm volatile("" : "+v"(idxs[k]));

    float acc[FOUT];
#pragma unroll
    for (int o = 0; o < FOUT; ++o) acc[o] = 0.f;

    f32x4 xw[9];                         // 9-slot rolling gather window

#define C1_ISSUE(tap, s) do {                                                \
        const float4* p_ = xpad + idxs[tap];                                 \
        asm volatile("global_load_dwordx4 %0, %1, off"                       \
                     : "=v"(xw[s]) : "v"(p_));                               \
    } while (0)

#pragma unroll
    for (int t = 0; t < 9; ++t) C1_ISSUE(t, t);      // prologue: 9 in flight

#pragma unroll
    for (int k = 0; k < KK; ++k) {
        const int rem = KK - 1 - k;
        if      (rem >= 8) asm volatile("s_waitcnt vmcnt(8)");
        else if (rem == 7) asm volatile("s_waitcnt vmcnt(7)");
        else if (rem == 6) asm volatile("s_waitcnt vmcnt(6)");
        else if (rem == 5) asm volatile("s_waitcnt vmcnt(5)");
        else if (rem == 4) asm volatile("s_waitcnt vmcnt(4)");
        else if (rem == 3) asm volatile("s_waitcnt vmcnt(3)");
        else if (rem == 2) asm volatile("s_waitcnt vmcnt(2)");
        else if (rem == 1) asm volatile("s_waitcnt vmcnt(1)");
        else               asm volatile("s_waitcnt vmcnt(0)");
        __builtin_amdgcn_sched_barrier(0);           // rule #18: pin the wait

        const int s = k % 9;
        const float xx = xw[s].x, xy = xw[s].y, xz = xw[s].z;
        const float* w = w1 + k * (FIN * FOUT);      // uniform -> s_load
#pragma unroll
        for (int o = 0; o < FOUT; ++o) {
            float a = acc[o];
            a = fmaf(xx, w[o],            a);
            a = fmaf(xy, w[FOUT + o],     a);
            a = fmaf(xz, w[2 * FOUT + o], a);
            acc[o] = a;
        }
        if (k + 9 < KK) C1_ISSUE(k + 9, s);          // refill freed slot
    }
#undef C1_ISSUE

    f16* hr = h_out + (size_t)n * FOUT;
#pragma unroll
    for (int g = 0; g < 4; ++g) {
        f16x8 hv;
#pragma unroll
        for (int j = 0; j < 8; ++j) {
            const int o = g * 8 + j;
            const float sc = g1[o] * rsqrtf(v1[o] + EPS);
            float v = (acc[o] - m1[o]) * sc + b1[o];
            v = v / (1.f + __expf(-v));              // silu
            hv[j] = (f16)v;
        }
        *(f16x8*)(hr + g * 8) = hv;                  // 16B stores
    }
}

// ---------------------------------------------------------------------------
// Dispatch 2 (MFMA): x_out = einsum(h[nbr_idx], w2) + fused point branch.
// THE DISCRIMINATING EXPERIMENT: B-frags (w2p, 54 KB) staged in LDS once per
// block -> the vmem stream in the k-loop is A-gathers ONLY (halved). If conv2
// was vmem-issue/probe-bound it drops to ~35 us; if it stays ~47 us with
// FETCH unchanged, the HBM random-64B-line floor is proven. A keeps the r8
// asm window (6 taps x 2 loads, counted vmcnt). B via compiler-scheduled
// ds_read_b128 with 1-tap prefetch rotation (compiler handles lgkmcnt).
// ---------------------------------------------------------------------------
__global__ __launch_bounds__(256, 2) void conv2_mfma_kernel(
    const f16*   __restrict__ h,         // [N,32] f16
    const int*   __restrict__ nbr_idx,   // [N,27]
    const f16*   __restrict__ w2p,       // packed [27][2][64][8] f16
    const float* __restrict__ z_feats,   // [N,3]
    const float* __restrict__ mlp_w,     // [3,32]
    const float* __restrict__ mlp_b,
    const float* __restrict__ mg, const float* __restrict__ mbe,
    const float* __restrict__ mm, const float* __restrict__ mv,
    float* __restrict__ out)             // [2,N,32]
{
    __shared__ f16 bsm[KK * 1024];       // 54 KiB: all B-frags

    const int t = threadIdx.x;
    {   // cooperative coalesced copy w2p -> LDS (3456 x 16B chunks)
        const f32x4* src = (const f32x4*)w2p;
        f32x4*       dst = (f32x4*)bsm;
#pragma unroll
        for (int i = 0; i < 13; ++i) dst[i * 256 + t] = src[i * 256 + t];
        if (t < 128) dst[3328 + t] = src[3328 + t];
    }
    __syncthreads();

    const int lane = t & 63;
    const int wave = t >> 6;
    const int base = (blockIdx.x * 4 + wave) * 32;   // this wave's node base
    const int row  = lane & 31;                      // A row
    const int hi   = lane >> 5;                      // contraction half of 8

    int idxs[KK];
    const int* nb = nbr_idx + (size_t)(base + row) * KK;
#pragma unroll
    for (int k = 0; k < KK; ++k) idxs[k] = nb[k];
#pragma unroll
    for (int k = 0; k < KK; ++k) asm volatile("" : "+v"(idxs[k]));

    f32x16 acc0 = {};                                // feats [0,16) partial
    f32x16 acc1 = {};                                // feats [16,32) partial

    f32x4 wa1[6], wa2[6];                            // 6-slot A window

#define C2_ISSUE(tp, s) do {                                                 \
        const f16* hr_ = h + (size_t)idxs[tp] * FOUT + hi * 8;               \
        asm volatile("global_load_dwordx4 %0, %1, off"                       \
                     : "=v"(wa1[s]) : "v"(hr_));                             \
        asm volatile("global_load_dwordx4 %0, %1, off offset:32"             \
                     : "=v"(wa2[s]) : "v"(hr_));                             \
    } while (0)

#pragma unroll
    for (int p = 0; p < 6; ++p) C2_ISSUE(p, p);      // prologue: 12 in flight

    const f16* bl = bsm + lane * 8;                  // per-lane B base (LDS)
    f16x8 b1 = *(const f16x8*)bl;                    // tap 0 B-frags
    f16x8 b2 = *(const f16x8*)(bl + 512);

#pragma unroll
    for (int k = 0; k < KK; ++k) {                   // fully unrolled
        const int rem = KK - 1 - k;                  // taps issued after k
        if      (rem >= 5) asm volatile("s_waitcnt vmcnt(10)");
        else if (rem == 4) asm volatile("s_waitcnt vmcnt(8)");
        else if (rem == 3) asm volatile("s_waitcnt vmcnt(6)");
        else if (rem == 2) asm volatile("s_waitcnt vmcnt(4)");
        else if (rem == 1) asm volatile("s_waitcnt vmcnt(2)");
        else               asm volatile("s_waitcnt vmcnt(0)");
        __builtin_amdgcn_sched_barrier(0);           // rule #18: pin the wait

        f16x8 nb1, nb2;                              // prefetch next-tap B
        if (k + 1 < KK) {
            nb1 = *(const f16x8*)(bl + (k + 1) * 1024);
            nb2 = *(const f16x8*)(bl + (k + 1) * 1024 + 512);
        }

        const int s = k % 6;
        const f16x8 a1 = __builtin_bit_cast(f16x8, wa1[s]);
        const f16x8 a2 = __builtin_bit_cast(f16x8, wa2[s]);
        __builtin_amdgcn_s_setprio(1);
        acc0 = __builtin_amdgcn_mfma_f32_32x32x16_f16(a1, b1, acc0, 0, 0, 0);
        acc1 = __builtin_amdgcn_mfma_f32_32x32x16_f16(a2, b2, acc1, 0, 0, 0);
        __builtin_amdgcn_s_setprio(0);

        if (k + 6 < KK) C2_ISSUE(k + 6, s);          // refill freed slot
        if (k + 1 < KK) { b1 = nb1; b2 = nb2; }
    }
#undef C2_ISSUE

    // ---- epilogue: point branch for output column n0, fused add + store ----
    const int n0 = lane & 31;
    const float wc0 = mlp_w[n0];
    const float wc1 = mlp_w[FOUT + n0];
    const float wc2 = mlp_w[2 * FOUT + n0];
    const float sc  = mg[n0] * rsqrtf(mv[n0] + EPS);
    const float bi  = mlp_b[n0];
    const float mmv = mm[n0];
    const float mbv = mbe[n0];

#pragma unroll
    for (int r = 0; r < 16; ++r) {
        const int m    = (r & 3) + ((r >> 2) << 3) + (hi << 2); // C/D row map
        const int node = base + m;
        const float* zr = z_feats + (size_t)node * FIN;
        float z = bi;
        z = fmaf(zr[0], wc0, z);
        z = fmaf(zr[1], wc1, z);
        z = fmaf(zr[2], wc2, z);
        z = (z - mmv) * sc + mbv;
        z = fmaxf(z, 0.f);
        const float v = acc0[r] + acc1[r] + z;
        out[(size_t)node * FOUT + n0] = v;
        out[(size_t)NN * FOUT + (size_t)node * FOUT + n0] = v;
    }
}

extern "C" void kernel_launch(void* const* d_in, const int* in_sizes, int n_in,
                              void* d_out, int out_size, void* d_ws, size_t ws_size,
                              hipStream_t stream) {
    const float* x_feats = (const float*)d_in[0];
    const float* z_feats = (const float*)d_in[1];
    const int*   nbr_idx = (const int*)d_in[2];
    const float* w1      = (const float*)d_in[3];
    const float* bn1_g   = (const float*)d_in[4];
    const float* bn1_b   = (const float*)d_in[5];
    const float* bn1_m   = (const float*)d_in[6];
    const float* bn1_v   = (const float*)d_in[7];
    const float* w2      = (const float*)d_in[8];
    const float* mlp_w   = (const float*)d_in[9];
    const float* mlp_b   = (const float*)d_in[10];
    const float* mlp_g   = (const float*)d_in[11];
    const float* mlp_be  = (const float*)d_in[12];
    const float* mlp_m   = (const float*)d_in[13];
    const float* mlp_v   = (const float*)d_in[14];

    // workspace: h [0,8M)  w2p [8M, 8M+55296)  xpad [9M, 11M)  (ws>=11M proven)
    f16*    h    = (f16*)d_ws;
    f16*    w2p  = (f16*)((char*)d_ws + (size_t)8 * 1024 * 1024);
    float4* xpad = (float4*)((char*)d_ws + (size_t)9 * 1024 * 1024);
    float*  out  = (float*)d_out;

    prep_kernel<<<NN / 256 + KK, 256, 0, stream>>>(x_feats, xpad, w2, w2p);
    conv1_kernel<<<NN / 256, 256, 0, stream>>>(
        xpad, nbr_idx, w1, bn1_g, bn1_b, bn1_m, bn1_v, h);
    conv2_mfma_kernel<<<NN / 128, 256, 0, stream>>>(
        h, nbr_idx, w2p, z_feats, mlp_w, mlp_b, mlp_g, mlp_be,
        mlp_m, mlp_v, out);
}